// Round 6
// baseline (107.981 us; speedup 1.0000x reference)
//
#include <hip/hip_runtime.h>
#include <hip/hip_bf16.h>
#include <stdint.h>

typedef __bf16  bf16x8 __attribute__((ext_vector_type(8)));
typedef __bf16  bf16x4 __attribute__((ext_vector_type(4)));
typedef float   f32x4  __attribute__((ext_vector_type(4)));
typedef uint32_t u32x4 __attribute__((ext_vector_type(4)));

#define SLEN  2048
#define DHEAD 128
#define QBLK  64            // 8 waves: 4 q-subtiles x 2 kv-groups
#define NQT   (SLEN / QBLK) // 32
#define THR   8.0f

__device__ __forceinline__ uint32_t cvt_pk(float lo, float hi2) {
    uint32_t u;
    asm("v_cvt_pk_bf16_f32 %0, %1, %2" : "=v"(u) : "v"(lo), "v"(hi2));
    return u;
}

__global__ __launch_bounds__(512, 4) void attn_fwd(
    const float* __restrict__ Q, const float* __restrict__ K,
    const float* __restrict__ V, float* __restrict__ O)
{
    const int bh = blockIdx.x;
    const int qt = (NQT - 1) - blockIdx.y;  // LPT: longest first
    const int tid  = threadIdx.x;
    const int w    = tid >> 6;     // 0..7
    const int tb   = w >> 2;       // kv group: 0 = even tiles, 1 = odd
    const int wq   = w & 3;        // q subtile
    const int lane = tid & 63;
    const int r    = lane & 15;
    const int g    = lane >> 4;

    const size_t head_off = (size_t)bh * SLEN * DHEAD;
    const float* Qh = Q + head_off;
    const float* Kh = K + head_off;
    const float* Vh = V + head_off;
    float*       Oh = O + head_off;

    const int q0w = qt * QBLK + wq * 16;

    // K buf b: smem + b*16384, [64][256B], swz col16 ^= (row&15)
    // Vt buf b: smem + 32768 + b*16384, [128][128B], swz slot16 ^= X(d)
    __shared__ __align__(16) char smem[65536];
    __shared__ float ml_sh[4][16][2];

    const float scale = 0.08838834764831845f;

    // ---- Q fragments (B operand): col = q0w + r, k = kb*32 + g*8 + e ----
    bf16x8 qfrag[4];
    {
        const float4* qp = reinterpret_cast<const float4*>(
            Qh + (size_t)(q0w + r) * DHEAD + g * 8);
        #pragma unroll
        for (int kb = 0; kb < 4; ++kb) {
            float4 a = qp[kb*8 + 0];
            float4 b = qp[kb*8 + 1];
            a.x*=scale; a.y*=scale; a.z*=scale; a.w*=scale;
            b.x*=scale; b.y*=scale; b.z*=scale; b.w*=scale;
            bf16x8 f;
            f[0]=(__bf16)a.x; f[1]=(__bf16)a.y; f[2]=(__bf16)a.z; f[3]=(__bf16)a.w;
            f[4]=(__bf16)b.x; f[5]=(__bf16)b.y; f[6]=(__bf16)b.z; f[7]=(__bf16)b.w;
            qfrag[kb] = f;
        }
    }

    // staging regs: 512 threads stage 64 kv rows of K and V
    float4 kreg[4], vreg[4];
    const int c4 = tid & 31;       // 16B column
    const int q6 = tid >> 5;       // 0..15: V kv-quad

    auto issue_loads = [&](int kv0) {
        #pragma unroll
        for (int it = 0; it < 4; ++it) {
            const int row = (it * 512 + tid) >> 5;
            kreg[it] = *reinterpret_cast<const float4*>(
                Kh + (size_t)(kv0 + row) * DHEAD + c4 * 4);
        }
        #pragma unroll
        for (int kr = 0; kr < 4; ++kr)
            vreg[kr] = *reinterpret_cast<const float4*>(
                Vh + (size_t)(kv0 + q6 * 4 + kr) * DHEAD + c4 * 4);
    };

    auto write_tiles = [&](int buf) {
        char* Kb  = smem + buf * 16384;
        char* Vtb = smem + 32768 + buf * 16384;
        #pragma unroll
        for (int it = 0; it < 4; ++it) {
            const int row = (it * 512 + tid) >> 5;
            bf16x4 k4;
            k4[0]=(__bf16)kreg[it].x; k4[1]=(__bf16)kreg[it].y;
            k4[2]=(__bf16)kreg[it].z; k4[3]=(__bf16)kreg[it].w;
            *reinterpret_cast<bf16x4*>(
                Kb + row * 256 + ((c4 * 8) ^ ((row & 15) << 4))) = k4;
        }
        #pragma unroll
        for (int j = 0; j < 4; ++j) {
            const int d = c4 * 4 + j;
            bf16x4 v4;
            #pragma unroll
            for (int kr = 0; kr < 4; ++kr)
                v4[kr] = (__bf16)((&vreg[kr].x)[j]);
            const int slot16 = (q6 >> 1) ^ ((c4 + 2*j) & 7);
            *reinterpret_cast<bf16x4*>(
                Vtb + d * 128 + (slot16 << 4) + ((q6 & 1) << 3)) = v4;
        }
    };

    const f32x4 vzero = {0.f, 0.f, 0.f, 0.f};
    f32x4 acc_o[8];
    #pragma unroll
    for (int i = 0; i < 8; ++i) acc_o[i] = vzero;
    float m_run = -1e30f, l_run = 0.f;

    issue_loads(0);
    write_tiles(0);

    const int n_iter = qt + 1;   // pairs of 32-kv tiles (even+odd)
    int cur = 0;

    for (int i = 0; i < n_iter; ++i) {
        __syncthreads();                         // buf[cur] ready
        if (i + 1 < n_iter) issue_loads((i + 1) * 64);

        const int kv0 = i * 64 + tb * 32;        // my wave's tile
        if (kv0 <= q0w + 15) {
            char* Kb  = smem + cur * 16384;
            char* Vtb = smem + 32768 + cur * 16384;
            const bool alive1 = (kv0 + 16 <= q0w + 15);

            // ---- swapped QK^T: S^T[kv][q]; lane owns q = q0w + r ----
            f32x4 st[2] = {vzero, vzero};
            __builtin_amdgcn_s_setprio(1);
            #pragma unroll
            for (int t = 0; t < 2; ++t) {
                if (t == 1 && !alive1) break;
                const int row = tb * 32 + t * 16 + r;   // buffer row
                #pragma unroll
                for (int kb = 0; kb < 4; ++kb) {
                    bf16x8 kf = *reinterpret_cast<const bf16x8*>(
                        Kb + row * 256 + ((kb*64 + g*16) ^ (r << 4)));
                    st[t] = __builtin_amdgcn_mfma_f32_16x16x32_bf16(
                        kf, qfrag[kb], st[t], 0, 0, 0);
                }
            }
            __builtin_amdgcn_s_setprio(0);

            // ---- mask + in-register online softmax ----
            const int q = q0w + r;
            float pmax = -1e30f;
            #pragma unroll
            for (int t = 0; t < 2; ++t) {
                if (t == 1 && !alive1) break;
                if (kv0 + t*16 + 15 > q0w) {
                    #pragma unroll
                    for (int j = 0; j < 4; ++j)
                        if (kv0 + t*16 + 4*g + j > q) st[t][j] = -1e30f;
                }
                #pragma unroll
                for (int j = 0; j < 4; ++j) pmax = fmaxf(pmax, st[t][j]);
            }
            pmax = fmaxf(pmax, __shfl_xor(pmax, 16));
            pmax = fmaxf(pmax, __shfl_xor(pmax, 32));

            if (__any(pmax > m_run + THR)) {     // rare (defer-max)
                const float m_new = fmaxf(m_run, pmax);
                const float corr  = __expf(m_run - m_new);
                l_run *= corr; m_run = m_new;
                #pragma unroll
                for (int reg = 0; reg < 4; ++reg) {
                    const float cr = __shfl(corr, 4*g + reg);
                    #pragma unroll
                    for (int dt = 0; dt < 8; ++dt) acc_o[dt][reg] *= cr;
                }
            }

            float rowsum = 0.f;
            #pragma unroll
            for (int t = 0; t < 2; ++t) {
                if (t == 1 && !alive1) break;
                #pragma unroll
                for (int j = 0; j < 4; ++j) {
                    const float p = __expf(st[t][j] - m_run);
                    st[t][j] = p;
                    rowsum += p;
                }
            }
            rowsum += __shfl_xor(rowsum, 16);
            rowsum += __shfl_xor(rowsum, 32);
            l_run += rowsum;

            // ---- P redistribute to A-fragment (k = g*8 + e) ----
            const uint32_t p00 = cvt_pk(st[0][0], st[0][1]);
            const uint32_t p01 = cvt_pk(st[0][2], st[0][3]);
            const uint32_t p10 = alive1 ? cvt_pk(st[1][0], st[1][1]) : 0u;
            const uint32_t p11 = alive1 ? cvt_pk(st[1][2], st[1][3]) : 0u;
            const int sA = r + ((2 * (g & 1)) << 4);
            const int sB = r + ((2 * (g & 1) + 1) << 4);
            u32x4 words;
            {
                const uint32_t lo0 = (uint32_t)__shfl((int)p00, sA);
                const uint32_t hi0 = (uint32_t)__shfl((int)p10, sA);
                const uint32_t lo1 = (uint32_t)__shfl((int)p01, sA);
                const uint32_t hi1 = (uint32_t)__shfl((int)p11, sA);
                const uint32_t lo2 = (uint32_t)__shfl((int)p00, sB);
                const uint32_t hi2 = (uint32_t)__shfl((int)p10, sB);
                const uint32_t lo3 = (uint32_t)__shfl((int)p01, sB);
                const uint32_t hi3 = (uint32_t)__shfl((int)p11, sB);
                words[0] = (g & 2) ? hi0 : lo0;
                words[1] = (g & 2) ? hi1 : lo1;
                words[2] = (g & 2) ? hi2 : lo2;
                words[3] = (g & 2) ? hi3 : lo3;
            }
            const bf16x8 pa = __builtin_bit_cast(bf16x8, words);

            // ---- PV: B = Vt[d = dt*16 + r][kv = tb*32 + g*8 ..] ----
            __builtin_amdgcn_s_setprio(1);
            #pragma unroll
            for (int dt = 0; dt < 8; ++dt) {
                const int d = dt * 16 + r;
                const int X = (dt*4 + (r >> 2) + 2*(r & 3)) & 7;
                const int slot16 = ((tb << 2) + g) ^ X;
                bf16x8 vf = *reinterpret_cast<const bf16x8*>(
                    Vtb + d * 128 + (slot16 << 4));
                acc_o[dt] = __builtin_amdgcn_mfma_f32_16x16x32_bf16(
                    pa, vf, acc_o[dt], 0, 0, 0);
            }
            __builtin_amdgcn_s_setprio(0);
        }

        if (i + 1 < n_iter) write_tiles(cur ^ 1);
        cur ^= 1;
    }

    // ================= merge kv-groups (A = tb0, B = tb1) =================
    __syncthreads();               // all PV reads done; smem reusable
    float* Om = reinterpret_cast<float*>(smem);   // [4][16][132] f32
    if (tb == 1) {
        if (g == 0) { ml_sh[wq][r][0] = m_run; ml_sh[wq][r][1] = l_run; }
        #pragma unroll
        for (int reg = 0; reg < 4; ++reg) {
            float* orow = Om + (wq * 16 + 4*g + reg) * 132 + r;
            #pragma unroll
            for (int dt = 0; dt < 8; ++dt)
                orow[dt * 16] = acc_o[dt][reg];
        }
    }
    __syncthreads();
    if (tb == 0) {
        #pragma unroll
        for (int reg = 0; reg < 4; ++reg) {
            const int ql = 4*g + reg;
            const float ma = __shfl(m_run, ql);
            const float la = __shfl(l_run, ql);
            const float mb = ml_sh[wq][ql][0];
            const float lb = ml_sh[wq][ql][1];
            const float ms = fmaxf(ma, mb);
            const float fa = __expf(ma - ms);
            const float fb = __expf(mb - ms);
            const float inv = 1.0f / (la * fa + lb * fb);
            const float* brow = Om + (wq * 16 + ql) * 132 + r;
            float* orow = Oh + (size_t)(q0w + ql) * DHEAD + r;
            #pragma unroll
            for (int dt = 0; dt < 8; ++dt)
                orow[dt * 16] = (acc_o[dt][reg] * fa + brow[dt * 16] * fb) * inv;
        }
    }
}

extern "C" void kernel_launch(void* const* d_in, const int* in_sizes, int n_in,
                              void* d_out, int out_size, void* d_ws, size_t ws_size,
                              hipStream_t stream) {
    const float* Q = (const float*)d_in[0];
    const float* K = (const float*)d_in[1];
    const float* V = (const float*)d_in[2];
    float* O = (float*)d_out;
    dim3 grid(32 /* B*H */, NQT);
    attn_fwd<<<grid, 512, 0, stream>>>(Q, K, V, O);
}

// Round 10
// 91.229 us; speedup vs baseline: 1.1836x; 1.1836x over previous
//
#include <hip/hip_runtime.h>
#include <hip/hip_bf16.h>
#include <stdint.h>

typedef __bf16  bf16x8 __attribute__((ext_vector_type(8)));
typedef __bf16  bf16x4 __attribute__((ext_vector_type(4)));
typedef float   f32x4  __attribute__((ext_vector_type(4)));
typedef uint32_t u32x4 __attribute__((ext_vector_type(4)));

#define SLEN  2048
#define DHEAD 128
#define QBLK  64            // 4 waves x 16 q-rows
#define KVBLK 32
#define NQT   (SLEN / QBLK) // 32
#define THR2  11.5415603f   // 8 * log2(e): defer-max threshold, exp2 domain

__device__ __forceinline__ uint32_t cvt_pk(float lo, float hi2) {
    uint32_t u;
    asm("v_cvt_pk_bf16_f32 %0, %1, %2" : "=v"(u) : "v"(lo), "v"(hi2));
    return u;
}

// native 2^x via builtin (compiler handles TRANS hazard waits)
__device__ __forceinline__ float exp2fast(float x) {
    return __builtin_amdgcn_exp2f(x);
}

__global__ __launch_bounds__(256, 3) void attn_fwd(
    const float* __restrict__ Q, const float* __restrict__ K,
    const float* __restrict__ V, float* __restrict__ O)
{
    const int bh = blockIdx.x;              // heads fastest
    const int qt = (NQT - 1) - blockIdx.y;  // LPT: longest first
    const int tid  = threadIdx.x;
    const int w    = tid >> 6;
    const int lane = tid & 63;
    const int r    = lane & 15;
    const int g    = lane >> 4;

    const size_t head_off = (size_t)bh * SLEN * DHEAD;
    const float* Qh = Q + head_off;
    const float* Kh = K + head_off;
    const float* Vh = V + head_off;
    float*       Oh = O + head_off;

    const int q0w = qt * QBLK + w * 16;     // wave's first q row

    __shared__ __bf16 K_sh [2][KVBLK * DHEAD];  // [32][256B], swz (row&15)<<4
    __shared__ __bf16 Vt_sh[2][DHEAD * 40];     // [128][80B], quad-xor swz

    // exp2-domain: fold log2(e) into the QK scale
    const float scale = 0.08838834764831845f * 1.4426950408889634f;

    // ---- Q fragments (B operand): col=q0w+r, k = kb*32 + g*8 + e ----
    bf16x8 qfrag[4];
    {
        const float4* qp = reinterpret_cast<const float4*>(
            Qh + (size_t)(q0w + r) * DHEAD + g * 8);
        #pragma unroll
        for (int kb = 0; kb < 4; ++kb) {
            float4 a = qp[kb*8 + 0];
            float4 b = qp[kb*8 + 1];
            a.x*=scale; a.y*=scale; a.z*=scale; a.w*=scale;
            b.x*=scale; b.y*=scale; b.z*=scale; b.w*=scale;
            bf16x8 f;
            f[0]=(__bf16)a.x; f[1]=(__bf16)a.y; f[2]=(__bf16)a.z; f[3]=(__bf16)a.w;
            f[4]=(__bf16)b.x; f[5]=(__bf16)b.y; f[6]=(__bf16)b.z; f[7]=(__bf16)b.w;
            qfrag[kb] = f;
        }
    }

    // staging regs
    float4 kreg[4], vreg[4];
    const int c4  = tid & 31;
    const int kvq = tid >> 5;        // 0..7: V kv-quad

    auto issue_loads = [&](int kv0) {
        #pragma unroll
        for (int it = 0; it < 4; ++it) {
            const int row = (it * 256 + tid) >> 5;
            kreg[it] = *reinterpret_cast<const float4*>(
                Kh + (size_t)(kv0 + row) * DHEAD + c4 * 4);
        }
        #pragma unroll
        for (int kr = 0; kr < 4; ++kr)
            vreg[kr] = *reinterpret_cast<const float4*>(
                Vh + (size_t)(kv0 + kvq * 4 + kr) * DHEAD + c4 * 4);
    };

    auto write_tiles = [&](int buf) {
        char* Kb  = reinterpret_cast<char*>(K_sh[buf]);
        char* Vtb = reinterpret_cast<char*>(Vt_sh[buf]);
        #pragma unroll
        for (int it = 0; it < 4; ++it) {
            const int row = (it * 256 + tid) >> 5;
            bf16x4 k4;
            k4[0]=(__bf16)kreg[it].x; k4[1]=(__bf16)kreg[it].y;
            k4[2]=(__bf16)kreg[it].z; k4[3]=(__bf16)kreg[it].w;
            *reinterpret_cast<bf16x4*>(
                Kb + row * 256 + ((c4 * 8) ^ ((row & 15) << 4))) = k4;
        }
        #pragma unroll
        for (int j = 0; j < 4; ++j) {
            const int d = c4 * 4 + j;
            bf16x4 v4;
            #pragma unroll
            for (int kr = 0; kr < 4; ++kr)
                v4[kr] = (__bf16)((&vreg[kr].x)[j]);
            *reinterpret_cast<bf16x4*>(
                Vtb + d * 80 + ((kvq ^ ((d >> 2) & 6)) * 8)) = v4;
        }
    };

    const f32x4 vzero = {0.f, 0.f, 0.f, 0.f};
    f32x4 acc_o[8];
    #pragma unroll
    for (int i = 0; i < 8; ++i) acc_o[i] = vzero;
    float m_run = -1e30f, l_run = 0.f;

    issue_loads(0);
    write_tiles(0);

    const int kvt_blk_max = 2 * qt + 1;
    const int kvt_max_w   = (q0w + 15) >> 5;
    int cur = 0;

    for (int kvt = 0; kvt <= kvt_blk_max; ++kvt) {
        __syncthreads();
        const bool more = (kvt < kvt_blk_max);
        if (more) issue_loads((kvt + 1) * KVBLK);

        if (kvt <= kvt_max_w) {
            const int kv0 = kvt * KVBLK;
            char* Kb  = reinterpret_cast<char*>(K_sh[cur]);
            char* Vtb = reinterpret_cast<char*>(Vt_sh[cur]);

            const bool alive1 = (kv0 + 16 <= q0w + 15);

            // ---- swapped QK^T: S^T[kv][q]; lane owns q = q0w + r ----
            f32x4 st[2] = {vzero, vzero};
            __builtin_amdgcn_s_setprio(1);
            #pragma unroll
            for (int t = 0; t < 2; ++t) {
                if (t == 1 && !alive1) break;
                const int row = t * 16 + r;
                #pragma unroll
                for (int kb = 0; kb < 4; ++kb) {
                    bf16x8 kf = *reinterpret_cast<const bf16x8*>(
                        Kb + row * 256 + ((kb*64 + g*16) ^ ((row & 15) << 4)));
                    st[t] = __builtin_amdgcn_mfma_f32_16x16x32_bf16(
                        kf, qfrag[kb], st[t], 0, 0, 0);
                }
            }
            __builtin_amdgcn_s_setprio(0);

            // ---- mask (lane's kv = kv0 + t*16 + 4g + j; q = q0w + r) ----
            const int q = q0w + r;
            float pmax = -1e30f;
            #pragma unroll
            for (int t = 0; t < 2; ++t) {
                if (t == 1 && !alive1) break;
                if (kv0 + t*16 + 15 > q0w) {
                    #pragma unroll
                    for (int j = 0; j < 4; ++j)
                        if (kv0 + t*16 + 4*g + j > q) st[t][j] = -1e30f;
                }
                #pragma unroll
                for (int j = 0; j < 4; ++j) pmax = fmaxf(pmax, st[t][j]);
            }
            pmax = fmaxf(pmax, __shfl_xor(pmax, 16));
            pmax = fmaxf(pmax, __shfl_xor(pmax, 32));

            if (__any(pmax > m_run + THR2)) {   // rare (defer-max)
                const float m_new = fmaxf(m_run, pmax);
                const float corr  = exp2fast(m_run - m_new);
                l_run *= corr; m_run = m_new;
                #pragma unroll
                for (int reg = 0; reg < 4; ++reg) {
                    const float cr = __shfl(corr, 4*g + reg); // acc q = q0w+4g+reg
                    #pragma unroll
                    for (int dt = 0; dt < 8; ++dt) acc_o[dt][reg] *= cr;
                }
            }

            float rowsum = 0.f;
            #pragma unroll
            for (int t = 0; t < 2; ++t) {
                if (t == 1 && !alive1) break;
                #pragma unroll
                for (int j = 0; j < 4; ++j) {
                    const float p = exp2fast(st[t][j] - m_run);
                    st[t][j] = p;
                    rowsum += p;
                }
            }
            rowsum += __shfl_xor(rowsum, 16);
            rowsum += __shfl_xor(rowsum, 32);
            l_run += rowsum;

            // ---- P redistribute: A-frag k = g*8+e ----
            const uint32_t p00 = cvt_pk(st[0][0], st[0][1]);
            const uint32_t p01 = cvt_pk(st[0][2], st[0][3]);
            const uint32_t p10 = alive1 ? cvt_pk(st[1][0], st[1][1]) : 0u;
            const uint32_t p11 = alive1 ? cvt_pk(st[1][2], st[1][3]) : 0u;
            const int sA = r + ((2 * (g & 1)) << 4);      // w = 0,1
            const int sB = r + ((2 * (g & 1) + 1) << 4);  // w = 2,3
            u32x4 words;
            {
                const uint32_t lo0 = (uint32_t)__shfl((int)p00, sA);
                const uint32_t hi0 = (uint32_t)__shfl((int)p10, sA);
                const uint32_t lo1 = (uint32_t)__shfl((int)p01, sA);
                const uint32_t hi1 = (uint32_t)__shfl((int)p11, sA);
                const uint32_t lo2 = (uint32_t)__shfl((int)p00, sB);
                const uint32_t hi2 = (uint32_t)__shfl((int)p10, sB);
                const uint32_t lo3 = (uint32_t)__shfl((int)p01, sB);
                const uint32_t hi3 = (uint32_t)__shfl((int)p11, sB);
                words[0] = (g & 2) ? hi0 : lo0;
                words[1] = (g & 2) ? hi1 : lo1;
                words[2] = (g & 2) ? hi2 : lo2;
                words[3] = (g & 2) ? hi3 : lo3;
            }
            const bf16x8 pa = __builtin_bit_cast(bf16x8, words);

            // ---- PV: B = Vt[d = dt*16 + r][kv = g*8 .. g*8+7] ----
            __builtin_amdgcn_s_setprio(1);
            #pragma unroll
            for (int dt = 0; dt < 8; ++dt) {
                const int d = dt * 16 + r;
                bf16x8 vf = *reinterpret_cast<const bf16x8*>(
                    Vtb + d * 80 + (((2*g) ^ ((d >> 2) & 6)) * 8));
                acc_o[dt] = __builtin_amdgcn_mfma_f32_16x16x32_bf16(
                    pa, vf, acc_o[dt], 0, 0, 0);
            }
            __builtin_amdgcn_s_setprio(0);
        }

        if (more) write_tiles(cur ^ 1);
        cur ^= 1;
    }

    // ---- epilogue: O[q0w + 4g + reg][dt*16 + r] = acc / l ----
    const float inv = 1.0f / l_run;
    #pragma unroll
    for (int reg = 0; reg < 4; ++reg) {
        const float iv = __shfl(inv, 4*g + reg);
        float* orow = Oh + (size_t)(q0w + 4*g + reg) * DHEAD + r;
        #pragma unroll
        for (int dt = 0; dt < 8; ++dt)
            orow[dt * 16] = acc_o[dt][reg] * iv;
    }
}

extern "C" void kernel_launch(void* const* d_in, const int* in_sizes, int n_in,
                              void* d_out, int out_size, void* d_ws, size_t ws_size,
                              hipStream_t stream) {
    const float* Q = (const float*)d_in[0];
    const float* K = (const float*)d_in[1];
    const float* V = (const float*)d_in[2];
    float* O = (float*)d_out;
    dim3 grid(32 /* B*H */, NQT);
    attn_fwd<<<grid, 256, 0, stream>>>(Q, K, V, O);
}